// Round 5
// baseline (56.376 us; speedup 1.0000x reference)
//
#include <hip/hip_runtime.h>

// AttMaxPool2D: x [B=32, W=128, H=128, C=128] fp32, pool 2x2 stride 2.
// out[b,wo,ho,c] = sum_k p_k * softmax_k(p_k * T) over the 2x2 patch.
//
// Memory-bound streaming op: 268 MB read + 67 MB write per call, zero
// intra-call reuse. Residency probe R4: protect only 128 MiB (batches
// [0,16), plain loads) -- half of L3 -- and stream the other 128 MiB
// (nt loads) + 64 MiB output (nt stores) through the remaining headroom.
// 8192 blocks (4x over-decomposition for scheduler backfill), 8:8
// cached:nt interleave per 16 blocks, 2 fully-unrolled iters/thread.

typedef float f32x4 __attribute__((ext_vector_type(4)));

__device__ __forceinline__ float att4(float a, float b, float c, float d, float T) {
    float sa = a * T, sb = b * T, sc = c * T, sd = d * T;
    float m  = fmaxf(fmaxf(sa, sb), fmaxf(sc, sd));
    float ea = __expf(sa - m);
    float eb = __expf(sb - m);
    float ec = __expf(sc - m);
    float ed = __expf(sd - m);
    float inv = 1.0f / (ea + eb + ec + ed);
    return (a * ea + b * eb + c * ec + d * ed) * inv;
}

__device__ __forceinline__ f32x4 attvec(f32x4 p0, f32x4 p1, f32x4 p2, f32x4 p3, float T) {
    f32x4 o;
    o.x = att4(p0.x, p1.x, p2.x, p3.x, T);
    o.y = att4(p0.y, p1.y, p2.y, p3.y, T);
    o.z = att4(p0.z, p1.z, p2.z, p3.z, T);
    o.w = att4(p0.w, p1.w, p2.w, p3.w, T);
    return o;
}

template<bool NT>
__device__ __forceinline__ f32x4 ld(const f32x4* p) {
    if constexpr (NT) return __builtin_nontemporal_load(p);
    else return *p;
}

// out f4 index i = b*131072 + wo*2048 + ho*32 + c4
// in  f4 index   = b*524288 + wo*8192 + ho*64 + c4
__device__ __forceinline__ int in_base(int i) {
    return ((i >> 11) << 13) + ((i & 2047) << 1) - (i & 31);
}

template<bool NT>
__device__ __forceinline__ void run_pair(const f32x4* __restrict__ x4,
                                         f32x4* __restrict__ out4,
                                         float T, int i, int j) {
    int bi = in_base(i);
    int bj = in_base(j);

    f32x4 a0 = ld<NT>(&x4[bi]);
    f32x4 a1 = ld<NT>(&x4[bi + 32]);
    f32x4 a2 = ld<NT>(&x4[bi + 4096]);
    f32x4 a3 = ld<NT>(&x4[bi + 4096 + 32]);
    f32x4 b0 = ld<NT>(&x4[bj]);
    f32x4 b1 = ld<NT>(&x4[bj + 32]);
    f32x4 b2 = ld<NT>(&x4[bj + 4096]);
    f32x4 b3 = ld<NT>(&x4[bj + 4096 + 32]);

    f32x4 oi = attvec(a0, a1, a2, a3, T);
    f32x4 oj = attvec(b0, b1, b2, b3, T);
    __builtin_nontemporal_store(oi, &out4[i]);
    __builtin_nontemporal_store(oj, &out4[j]);
}

// Region split (out-f4 units): cached = batches [0,16) -> 16*131072 = 2097152.
// 8192 blocks = 512 groups of 16 (8 cached : 8 nt).
// each side: 512*8*256 threads * 2 iters = 2097152 (exact)
#define I_CACHED     2097152
#define SIDE_THREADS (512 * 8 * 256)

__global__ __launch_bounds__(256, 8) void attpool2x2_kernel(
    const f32x4* __restrict__ x4,
    const float* __restrict__ temp,
    f32x4* __restrict__ out4)
{
    const float T = temp[0];
    int rb  = blockIdx.x & 15;
    int grp = blockIdx.x >> 4;   // 0..511

    if (rb < 8) {
        int rank = (grp * 8 + rb) * 256 + (int)threadIdx.x;
        run_pair<false>(x4, out4, T, rank, rank + SIDE_THREADS);
    } else {
        int rank = (grp * 8 + (rb - 8)) * 256 + (int)threadIdx.x;
        run_pair<true>(x4, out4, T, I_CACHED + rank, I_CACHED + rank + SIDE_THREADS);
    }
}

extern "C" void kernel_launch(void* const* d_in, const int* in_sizes, int n_in,
                              void* d_out, int out_size, void* d_ws, size_t ws_size,
                              hipStream_t stream) {
    const f32x4* x4   = (const f32x4*)d_in[0];
    const float* temp = (const float*)d_in[1];
    f32x4*       out4 = (f32x4*)d_out;

    attpool2x2_kernel<<<8192, 256, 0, stream>>>(x4, temp, out4);
}

// Round 6
// 52.291 us; speedup vs baseline: 1.0781x; 1.0781x over previous
//
#include <hip/hip_runtime.h>

// AttMaxPool2D: x [B=32, W=128, H=128, C=128] fp32, pool 2x2 stride 2.
// out[b,wo,ho,c] = sum_k p_k * softmax_k(p_k * T) over the 2x2 patch.
//
// Memory-bound streaming op: 268 MB read + 67 MB write per call, zero
// intra-call reuse. Residency-curve probe R5: protect 208 MiB (batches
// [0,26), plain loads -> L3-allocating) and nt-stream the remaining
// 48 MiB input + 64 MiB output. Curve so far: 128 MiB plain = 56.4 us,
// 176 MiB plain = 53.2 us; this samples 208 MiB.
// 8192 blocks (4x over-decomposition for backfill), 26:6 interleave per
// 32 blocks, 2 fully-unrolled iterations/thread, exact work split.

typedef float f32x4 __attribute__((ext_vector_type(4)));

__device__ __forceinline__ float att4(float a, float b, float c, float d, float T) {
    float sa = a * T, sb = b * T, sc = c * T, sd = d * T;
    float m  = fmaxf(fmaxf(sa, sb), fmaxf(sc, sd));
    float ea = __expf(sa - m);
    float eb = __expf(sb - m);
    float ec = __expf(sc - m);
    float ed = __expf(sd - m);
    float inv = 1.0f / (ea + eb + ec + ed);
    return (a * ea + b * eb + c * ec + d * ed) * inv;
}

__device__ __forceinline__ f32x4 attvec(f32x4 p0, f32x4 p1, f32x4 p2, f32x4 p3, float T) {
    f32x4 o;
    o.x = att4(p0.x, p1.x, p2.x, p3.x, T);
    o.y = att4(p0.y, p1.y, p2.y, p3.y, T);
    o.z = att4(p0.z, p1.z, p2.z, p3.z, T);
    o.w = att4(p0.w, p1.w, p2.w, p3.w, T);
    return o;
}

template<bool NT>
__device__ __forceinline__ f32x4 ld(const f32x4* p) {
    if constexpr (NT) return __builtin_nontemporal_load(p);
    else return *p;
}

// out f4 index i = b*131072 + wo*2048 + ho*32 + c4
// in  f4 index   = b*524288 + wo*8192 + ho*64 + c4
__device__ __forceinline__ int in_base(int i) {
    return ((i >> 11) << 13) + ((i & 2047) << 1) - (i & 31);
}

template<bool NT>
__device__ __forceinline__ void run_pair(const f32x4* __restrict__ x4,
                                         f32x4* __restrict__ out4,
                                         float T, int i, int j) {
    int bi = in_base(i);
    int bj = in_base(j);

    f32x4 a0 = ld<NT>(&x4[bi]);
    f32x4 a1 = ld<NT>(&x4[bi + 32]);
    f32x4 a2 = ld<NT>(&x4[bi + 4096]);
    f32x4 a3 = ld<NT>(&x4[bi + 4096 + 32]);
    f32x4 b0 = ld<NT>(&x4[bj]);
    f32x4 b1 = ld<NT>(&x4[bj + 32]);
    f32x4 b2 = ld<NT>(&x4[bj + 4096]);
    f32x4 b3 = ld<NT>(&x4[bj + 4096 + 32]);

    f32x4 oi = attvec(a0, a1, a2, a3, T);
    f32x4 oj = attvec(b0, b1, b2, b3, T);
    __builtin_nontemporal_store(oi, &out4[i]);
    __builtin_nontemporal_store(oj, &out4[j]);
}

// Region split (out-f4 units): cached = batches [0,26) -> 26*131072 = 3407872.
// 8192 blocks = 256 groups of 32 (26 cached : 6 nt).
// cached: 256*26*256 threads * 2 iters = 3407872 (exact)
// nt:     256*6*256  threads * 2 iters =  786432 (exact)
#define I_CACHED   3407872
#define NTHR_C     (256 * 26 * 256)
#define NTHR_NT    (256 * 6 * 256)

__global__ __launch_bounds__(256, 8) void attpool2x2_kernel(
    const f32x4* __restrict__ x4,
    const float* __restrict__ temp,
    f32x4* __restrict__ out4)
{
    const float T = temp[0];
    int rb  = blockIdx.x & 31;
    int grp = blockIdx.x >> 5;   // 0..255

    if (rb < 26) {
        int rank = (grp * 26 + rb) * 256 + (int)threadIdx.x;
        run_pair<false>(x4, out4, T, rank, rank + NTHR_C);
    } else {
        int rank = (grp * 6 + (rb - 26)) * 256 + (int)threadIdx.x;
        run_pair<true>(x4, out4, T, I_CACHED + rank, I_CACHED + rank + NTHR_NT);
    }
}

extern "C" void kernel_launch(void* const* d_in, const int* in_sizes, int n_in,
                              void* d_out, int out_size, void* d_ws, size_t ws_size,
                              hipStream_t stream) {
    const f32x4* x4   = (const f32x4*)d_in[0];
    const float* temp = (const float*)d_in[1];
    f32x4*       out4 = (f32x4*)d_out;

    attpool2x2_kernel<<<8192, 256, 0, stream>>>(x4, temp, out4);
}

// Round 7
// 52.196 us; speedup vs baseline: 1.0801x; 1.0018x over previous
//
#include <hip/hip_runtime.h>

// AttMaxPool2D: x [B=32, W=128, H=128, C=128] fp32, pool 2x2 stride 2.
// out[b,wo,ho,c] = sum_k p_k * softmax_k(p_k * T) over the 2x2 patch.
//
// Memory-bound streaming op: 268 MB read + 67 MB write per call.
// Residency-curve endpoint R6: ALL input loads plain (L3-allocating,
// 256 MiB == L3 size), output stores nontemporal (keep 64 MiB of writes
// out of L3). Curve: 128 MiB plain=56.4us, 176=53.2, 208=52.3 -> sample
// 256. Uniform work (no block classes), 8192 blocks x 256 thr x 2
// fully-unrolled iters = exact cover; over-decomposed 4x for backfill.

typedef float f32x4 __attribute__((ext_vector_type(4)));

__device__ __forceinline__ float att4(float a, float b, float c, float d, float T) {
    float sa = a * T, sb = b * T, sc = c * T, sd = d * T;
    float m  = fmaxf(fmaxf(sa, sb), fmaxf(sc, sd));
    float ea = __expf(sa - m);
    float eb = __expf(sb - m);
    float ec = __expf(sc - m);
    float ed = __expf(sd - m);
    float inv = 1.0f / (ea + eb + ec + ed);
    return (a * ea + b * eb + c * ec + d * ed) * inv;
}

__device__ __forceinline__ f32x4 attvec(f32x4 p0, f32x4 p1, f32x4 p2, f32x4 p3, float T) {
    f32x4 o;
    o.x = att4(p0.x, p1.x, p2.x, p3.x, T);
    o.y = att4(p0.y, p1.y, p2.y, p3.y, T);
    o.z = att4(p0.z, p1.z, p2.z, p3.z, T);
    o.w = att4(p0.w, p1.w, p2.w, p3.w, T);
    return o;
}

// out f4 index i = b*131072 + wo*2048 + ho*32 + c4
// in  f4 index   = b*524288 + wo*8192 + ho*64 + c4
__device__ __forceinline__ int in_base(int i) {
    return ((i >> 11) << 13) + ((i & 2047) << 1) - (i & 31);
}

#define NTHREADS (8192 * 256)

__global__ __launch_bounds__(256, 8) void attpool2x2_kernel(
    const f32x4* __restrict__ x4,
    const float* __restrict__ temp,
    f32x4* __restrict__ out4)
{
    const float T = temp[0];
    int i = blockIdx.x * 256 + (int)threadIdx.x;
    int j = i + NTHREADS;

    int bi = in_base(i);
    int bj = in_base(j);

    f32x4 a0 = x4[bi];
    f32x4 a1 = x4[bi + 32];
    f32x4 a2 = x4[bi + 4096];
    f32x4 a3 = x4[bi + 4096 + 32];
    f32x4 b0 = x4[bj];
    f32x4 b1 = x4[bj + 32];
    f32x4 b2 = x4[bj + 4096];
    f32x4 b3 = x4[bj + 4096 + 32];

    f32x4 oi = attvec(a0, a1, a2, a3, T);
    f32x4 oj = attvec(b0, b1, b2, b3, T);
    __builtin_nontemporal_store(oi, &out4[i]);
    __builtin_nontemporal_store(oj, &out4[j]);
}

extern "C" void kernel_launch(void* const* d_in, const int* in_sizes, int n_in,
                              void* d_out, int out_size, void* d_ws, size_t ws_size,
                              hipStream_t stream) {
    const f32x4* x4   = (const f32x4*)d_in[0];
    const float* temp = (const float*)d_in[1];
    f32x4*       out4 = (f32x4*)d_out;

    attpool2x2_kernel<<<8192, 256, 0, stream>>>(x4, temp, out4);
}